// Round 3
// baseline (65.923 us; speedup 1.0000x reference)
//
#include <hip/hip_runtime.h>
#include <stdint.h>

// Problem constants (from reference)
#define N_AG   8
#define S_SAMP 16
#define TB     8192      // T*B
#define DST    128       // D_STATE
#define E_DIM  64
#define HH_DIM 128

#define ST_PAD 68        // padded LDS stride for 64-row transposed A tile (16B-aligned)

__device__ __forceinline__ float4 ld4(const float* p) { return *(const float4*)p; }

// ---------------- JAX threefry2x32 (20 rounds) ----------------
__device__ __forceinline__ uint2 tf2x32(uint32_t k0, uint32_t k1,
                                        uint32_t c0, uint32_t c1) {
  uint32_t ks2 = k0 ^ k1 ^ 0x1BD11BDAu;
  uint32_t x0 = c0 + k0, x1 = c1 + k1;
#define TFR(r) { x0 += x1; x1 = (x1 << (r)) | (x1 >> (32 - (r))); x1 ^= x0; }
  TFR(13) TFR(15) TFR(26) TFR(6)
  x0 += k1;  x1 += ks2 + 1u;
  TFR(17) TFR(29) TFR(16) TFR(24)
  x0 += ks2; x1 += k0 + 2u;
  TFR(13) TFR(15) TFR(26) TFR(6)
  x0 += k0;  x1 += k1 + 3u;
  TFR(17) TFR(29) TFR(16) TFR(24)
  x0 += k1;  x1 += ks2 + 4u;
  TFR(13) TFR(15) TFR(26) TFR(6)
  x0 += ks2; x1 += k0 + 5u;
#undef TFR
  return make_uint2(x0, x1);
}

// ================= GEMM tile: 64 rows x 64 cols, K=128, 256 threads ==========
// ACT: 0=none, 1=relu, 2=abs.  W/bias pointers pre-offset to this chunk's col 0.
template<int LDW, int ACT>
__device__ __forceinline__ void gemm_64x64(const float s_T[DST][ST_PAD],
    const float* __restrict__ W, const float* __restrict__ bias,
    float* __restrict__ outp, int ldo, int outbase, int row0, int tid)
{
  const int c0  = (tid & 15) * 4;        // 16 col-groups * 4 cols
  const int rg0 = (tid >> 4) * 4;        // 16 row-groups * 4 rows
  float acc[4][4];
#pragma unroll
  for (int i = 0; i < 4; ++i)
#pragma unroll
    for (int j = 0; j < 4; ++j) acc[i][j] = 0.f;

  const float* wp = W + c0;
#pragma unroll 4
  for (int k = 0; k < DST; ++k) {
    float4 av = ld4(&s_T[k][rg0]);
    float4 wv = ld4(wp);
    wp += LDW;
    acc[0][0] = fmaf(av.x, wv.x, acc[0][0]);
    acc[0][1] = fmaf(av.x, wv.y, acc[0][1]);
    acc[0][2] = fmaf(av.x, wv.z, acc[0][2]);
    acc[0][3] = fmaf(av.x, wv.w, acc[0][3]);
    acc[1][0] = fmaf(av.y, wv.x, acc[1][0]);
    acc[1][1] = fmaf(av.y, wv.y, acc[1][1]);
    acc[1][2] = fmaf(av.y, wv.z, acc[1][2]);
    acc[1][3] = fmaf(av.y, wv.w, acc[1][3]);
    acc[2][0] = fmaf(av.z, wv.x, acc[2][0]);
    acc[2][1] = fmaf(av.z, wv.y, acc[2][1]);
    acc[2][2] = fmaf(av.z, wv.z, acc[2][2]);
    acc[2][3] = fmaf(av.z, wv.w, acc[2][3]);
    acc[3][0] = fmaf(av.w, wv.x, acc[3][0]);
    acc[3][1] = fmaf(av.w, wv.y, acc[3][1]);
    acc[3][2] = fmaf(av.w, wv.z, acc[3][2]);
    acc[3][3] = fmaf(av.w, wv.w, acc[3][3]);
  }
  const float4 bv = ld4(&bias[c0]);
#pragma unroll
  for (int i = 0; i < 4; ++i) {
    float x = acc[i][0] + bv.x, y = acc[i][1] + bv.y;
    float z = acc[i][2] + bv.z, w = acc[i][3] + bv.w;
    if (ACT == 1) { x = fmaxf(x, 0.f); y = fmaxf(y, 0.f); z = fmaxf(z, 0.f); w = fmaxf(w, 0.f); }
    if (ACT == 2) { x = fabsf(x); y = fabsf(y); z = fabsf(z); w = fabsf(w); }
    const int row = row0 + rg0 + i;
    *(float4*)&outp[(size_t)row * ldo + outbase + c0] = make_float4(x, y, z, w);
  }
}

// ============ K1a: layer-1 of all hypernets.  h_ws[8192][384] =
//  [0..128) relu(s@hw1_k1+b) | [128..256) relu(s@hw2_k1+b)
//  [256..320) relu(s@hb2_k1+b) | [320..384) s@b1_k+b  ============
__global__ __launch_bounds__(256)
void hyper_l1(const float* __restrict__ states,
              const float* __restrict__ hw1_k1, const float* __restrict__ hw1_b1,
              const float* __restrict__ b1_k,   const float* __restrict__ b1_b,
              const float* __restrict__ hw2_k1, const float* __restrict__ hw2_b1,
              const float* __restrict__ hb2_k1, const float* __restrict__ hb2_b1,
              float* __restrict__ h_ws)
{
  __shared__ float s_T[DST][ST_PAD];
  const int tid = threadIdx.x;
  const int row0 = blockIdx.x * 64;
  {
    const int r = tid & 63, kq = tid >> 6;   // 64 rows x 4 k-chunks of 32
    const float* srow = states + (size_t)(row0 + r) * DST + kq * 32;
#pragma unroll
    for (int j = 0; j < 8; ++j) {
      float4 v = ld4(srow + j * 4);
      const int k = kq * 32 + j * 4;
      s_T[k + 0][r] = v.x; s_T[k + 1][r] = v.y;
      s_T[k + 2][r] = v.z; s_T[k + 3][r] = v.w;
    }
  }
  __syncthreads();
  switch (blockIdx.y) {
    case 0: gemm_64x64<128, 1>(s_T, hw1_k1,      hw1_b1,      h_ws, 384, 0,   row0, tid); break;
    case 1: gemm_64x64<128, 1>(s_T, hw1_k1 + 64, hw1_b1 + 64, h_ws, 384, 64,  row0, tid); break;
    case 2: gemm_64x64<128, 1>(s_T, hw2_k1,      hw2_b1,      h_ws, 384, 128, row0, tid); break;
    case 3: gemm_64x64<128, 1>(s_T, hw2_k1 + 64, hw2_b1 + 64, h_ws, 384, 192, row0, tid); break;
    case 4: gemm_64x64<64,  1>(s_T, hb2_k1,      hb2_b1,      h_ws, 384, 256, row0, tid); break;
    default: gemm_64x64<64, 0>(s_T, b1_k,        b1_b,        h_ws, 384, 320, row0, tid); break;
  }
}

// ============ K1b: layer-2.  w_ws[8192][192] =
//  [0..128) |h1@hw1_k2+b| | [128..192) |h2@hw2_k2+b|  ============
__global__ __launch_bounds__(256)
void hyper_l2(const float* __restrict__ h_ws,
              const float* __restrict__ hw1_k2, const float* __restrict__ hw1_b2,
              const float* __restrict__ hw2_k2, const float* __restrict__ hw2_b2,
              float* __restrict__ w_ws)
{
  __shared__ float s_T[DST][ST_PAD];
  const int tid = threadIdx.x;
  const int row0 = blockIdx.x * 64;
  const int abase = (blockIdx.y == 2) ? 128 : 0;   // h1 vs h2
  {
    const int r = tid & 63, kq = tid >> 6;
    const float* srow = h_ws + (size_t)(row0 + r) * 384 + abase + kq * 32;
#pragma unroll
    for (int j = 0; j < 8; ++j) {
      float4 v = ld4(srow + j * 4);
      const int k = kq * 32 + j * 4;
      s_T[k + 0][r] = v.x; s_T[k + 1][r] = v.y;
      s_T[k + 2][r] = v.z; s_T[k + 3][r] = v.w;
    }
  }
  __syncthreads();
  switch (blockIdx.y) {
    case 0: gemm_64x64<128, 2>(s_T, hw1_k2,      hw1_b2,      w_ws, 192, 0,   row0, tid); break;
    case 1: gemm_64x64<128, 2>(s_T, hw1_k2 + 64, hw1_b2 + 64, w_ws, 192, 64,  row0, tid); break;
    default: gemm_64x64<64, 2>(s_T, hw2_k2,      hw2_b2,      w_ws, 192, 128, row0, tid); break;
  }
}

// ============ K2: RNG + ELU main loop + sample-mean ============
// v2: thread = (row, sample); computes ALL 8 agents per weight chunk so each
// ds_read_b128 is amortized 8x.  LDS strides padded (132/68) so the 4 distinct
// rows per wave broadcast from disjoint bank groups.
#define RPB2 16
#define W1_PAD 132
#define E_PAD  68
__global__ __launch_bounds__(256)
void alpha_main(const float* __restrict__ q_vals, const float* __restrict__ h_ws,
                const float* __restrict__ w_ws,  const float* __restrict__ hb2_k2,
                const float* __restrict__ hb2_b2, float* __restrict__ out)
{
  __shared__ float w1l[RPB2][W1_PAD];           // [r][0..128) : w1a | w1b
  __shared__ float b1l[RPB2][E_PAD];
  __shared__ float w2l[RPB2][E_PAD];
  __shared__ float hbl[RPB2][E_PAD];
  __shared__ float b2l[RPB2];
  __shared__ float ql[RPB2][N_AG];
  __shared__ float cnl[RPB2][S_SAMP][N_AG];
  __shared__ float red[RPB2][S_SAMP][N_AG];

  const int tid = threadIdx.x;
  const int row0 = blockIdx.x * RPB2;

  {  // w1: 16 rows * 128 = 512 float4, 2 per thread
    int idx = tid;
    int r = idx >> 5, c = (idx & 31) * 4;
    *(float4*)&w1l[r][c] = ld4(&w_ws[(size_t)(row0 + r) * 192 + c]);
    idx = tid + 256; r = idx >> 5; c = (idx & 31) * 4;
    *(float4*)&w1l[r][c] = ld4(&w_ws[(size_t)(row0 + r) * 192 + c]);
  }
  {  // b1 / w2 / hb: 256 float4 each, 1 per thread
    const int r = tid >> 4, c = (tid & 15) * 4;
    *(float4*)&b1l[r][c] = ld4(&h_ws[(size_t)(row0 + r) * 384 + 320 + c]);
    *(float4*)&w2l[r][c] = ld4(&w_ws[(size_t)(row0 + r) * 192 + 128 + c]);
    *(float4*)&hbl[r][c] = ld4(&h_ws[(size_t)(row0 + r) * 384 + 256 + c]);
  }
  if (tid < RPB2 * N_AG) {
    const int r = tid >> 3, a = tid & 7;
    ql[r][a] = q_vals[a * TB + row0 + r];
  }
  __syncthreads();

  const int r  = tid >> 4;      // row within block
  const int sl = tid & 15;      // sample
  // ---- b2[r] via 16-lane partial + shuffle ----
  {
    float v = hbl[r][sl]      * hb2_k2[sl]
            + hbl[r][sl + 16] * hb2_k2[sl + 16]
            + hbl[r][sl + 32] * hb2_k2[sl + 32]
            + hbl[r][sl + 48] * hb2_k2[sl + 48];
    v += __shfl_down(v, 8, 16); v += __shfl_down(v, 4, 16);
    v += __shfl_down(v, 2, 16); v += __shfl_down(v, 1, 16);
    if (sl == 0) b2l[r] = v + hb2_b2[0];
  }
  // ---- RNG: one (row, sample) per thread (verified chain) ----
  {
    const uint32_t j = (uint32_t)(row0 + r) * (uint32_t)S_SAMP + (uint32_t)sl;
    uint2 kj  = tf2x32(0u, 42u, 0u, j);       // partitionable split of key(42)
    uint2 sub = tf2x32(kj.x, kj.y, 0u, 1u);   // subkey = split(key_j)[1]
    uint32_t K[N_AG];
#pragma unroll
    for (int i = 0; i < N_AG; ++i) {
      uint2 b = tf2x32(sub.x, sub.y, 0u, (uint32_t)i);
      K[i] = b.x ^ b.y;
    }
    int posa[N_AG];
#pragma unroll
    for (int i = 0; i < N_AG; ++i) {
      int rank = 0;
#pragma unroll
      for (int m = 0; m < N_AG; ++m)
        rank += (K[m] < K[i]) || (K[m] == K[i] && m < i);
      posa[rank] = i;
    }
#pragma unroll
    for (int a = 0; a < N_AG; ++a) {
      const int pa = posa[a];
      float cs = 0.f;
#pragma unroll
      for (int a2 = 0; a2 < N_AG; ++a2)
        cs += (posa[a2] < pa) ? ql[r][a2] : 0.f;
      cnl[r][sl][a] = cs / (float)max(pa, 1);
    }
  }
  __syncthreads();

  // ---- main ELU loop: thread (r, s) does all 8 agents ----
  {
    float cn[N_AG], qv[N_AG], y[N_AG];
#pragma unroll
    for (int a = 0; a < N_AG; ++a) {
      cn[a] = cnl[r][sl][a];
      qv[a] = ql[r][a];
      y[a]  = 0.f;
    }
#pragma unroll
    for (int e = 0; e < E_DIM; e += 4) {
      const float4 wa  = ld4(&w1l[r][e]);
      const float4 wb  = ld4(&w1l[r][64 + e]);
      const float4 bb  = ld4(&b1l[r][e]);
      const float4 w2v = ld4(&w2l[r][e]);
#pragma unroll
      for (int a = 0; a < N_AG; ++a) {
        float h;
        h = fmaf(cn[a], wa.x, fmaf(qv[a], wb.x, bb.x));
        y[a] = fmaf((h > 0.f) ? h : (__expf(h) - 1.f), w2v.x, y[a]);
        h = fmaf(cn[a], wa.y, fmaf(qv[a], wb.y, bb.y));
        y[a] = fmaf((h > 0.f) ? h : (__expf(h) - 1.f), w2v.y, y[a]);
        h = fmaf(cn[a], wa.z, fmaf(qv[a], wb.z, bb.z));
        y[a] = fmaf((h > 0.f) ? h : (__expf(h) - 1.f), w2v.z, y[a]);
        h = fmaf(cn[a], wa.w, fmaf(qv[a], wb.w, bb.w));
        y[a] = fmaf((h > 0.f) ? h : (__expf(h) - 1.f), w2v.w, y[a]);
      }
    }
    const float b2v = b2l[r];
#pragma unroll
    for (int a = 0; a < N_AG; ++a) red[r][sl][a] = fabsf(y[a] + b2v);
  }
  __syncthreads();

  if (tid < RPB2 * N_AG) {
    const int rr = tid >> 3, a = tid & 7;
    float acc = 0.f;
#pragma unroll
    for (int ss = 0; ss < S_SAMP; ++ss) acc += red[rr][ss][a];
    out[a * TB + row0 + rr] = acc * (1.0f / (float)S_SAMP);
  }
}

// ===================== Fallback: round-1 fused kernel (proven) =====================
#define RPB 8
__global__ __launch_bounds__(256)
void alpha_fused_kernel(const float* __restrict__ q_vals, const float* __restrict__ states,
                        const float* __restrict__ hw1_k1, const float* __restrict__ hw1_b1,
                        const float* __restrict__ hw1_k2, const float* __restrict__ hw1_b2,
                        const float* __restrict__ b1_k,   const float* __restrict__ b1_b,
                        const float* __restrict__ hw2_k1, const float* __restrict__ hw2_b1,
                        const float* __restrict__ hw2_k2, const float* __restrict__ hw2_b2,
                        const float* __restrict__ hb2_k1, const float* __restrict__ hb2_b1,
                        const float* __restrict__ hb2_k2, const float* __restrict__ hb2_b2,
                        float* __restrict__ out)
{
  __shared__ float s_lds[RPB][DST];
  __shared__ float scratch[RPB][HH_DIM];
  __shared__ float scratch2[RPB][E_DIM];
  __shared__ float w1_lds[RPB][2 * E_DIM];
  __shared__ float b1_lds[RPB][E_DIM];
  __shared__ float w2_lds[RPB][E_DIM];
  __shared__ float b2_lds[RPB];
  __shared__ float q_lds[RPB][N_AG];
  __shared__ float cn_lds[RPB][S_SAMP][N_AG];
  __shared__ float red[RPB][S_SAMP * N_AG];
  const int tid = threadIdx.x;
  const int row0 = blockIdx.x * RPB;
  {
    const float4* src = reinterpret_cast<const float4*>(states + (size_t)row0 * DST);
    reinterpret_cast<float4*>(&s_lds[0][0])[tid] = src[tid];
  }
  if (tid < RPB * N_AG) {
    int r = tid >> 3, a = tid & 7;
    q_lds[r][a] = q_vals[a * TB + row0 + r];
  }
  __syncthreads();
  if (tid < RPB * S_SAMP) {
    int r = tid >> 4, s = tid & 15;
    uint32_t j = (uint32_t)(row0 + r) * (uint32_t)S_SAMP + (uint32_t)s;
    uint2 kj = tf2x32(0u, 42u, 0u, j);
    uint2 sub = tf2x32(kj.x, kj.y, 0u, 1u);
    uint32_t K[N_AG];
#pragma unroll
    for (int i = 0; i < N_AG; ++i) { uint2 b = tf2x32(sub.x, sub.y, 0u, (uint32_t)i); K[i] = b.x ^ b.y; }
    int posa[N_AG];
#pragma unroll
    for (int i = 0; i < N_AG; ++i) {
      int rank = 0;
#pragma unroll
      for (int m = 0; m < N_AG; ++m) rank += (K[m] < K[i]) || (K[m] == K[i] && m < i);
      posa[rank] = i;
    }
#pragma unroll
    for (int a = 0; a < N_AG; ++a) {
      int pa = posa[a];
      float cs = 0.f;
#pragma unroll
      for (int a2 = 0; a2 < N_AG; ++a2) cs += (posa[a2] < pa) ? q_lds[r][a2] : 0.f;
      cn_lds[r][s][a] = cs / (float)max(pa, 1);
    }
  }
  {
    int c = tid & 127, rg = tid >> 7;
    float a0 = 0.f, a1 = 0.f, a2 = 0.f, a3 = 0.f;
#pragma unroll 4
    for (int k = 0; k < DST; ++k) {
      float wv = hw1_k1[k * HH_DIM + c];
      a0 += s_lds[rg * 4 + 0][k] * wv; a1 += s_lds[rg * 4 + 1][k] * wv;
      a2 += s_lds[rg * 4 + 2][k] * wv; a3 += s_lds[rg * 4 + 3][k] * wv;
    }
    float b = hw1_b1[c];
    scratch[rg * 4 + 0][c] = fmaxf(a0 + b, 0.f); scratch[rg * 4 + 1][c] = fmaxf(a1 + b, 0.f);
    scratch[rg * 4 + 2][c] = fmaxf(a2 + b, 0.f); scratch[rg * 4 + 3][c] = fmaxf(a3 + b, 0.f);
  }
  {
    int c = tid & 63, rg = tid >> 6;
    float a0 = 0.f, a1 = 0.f;
#pragma unroll 4
    for (int k = 0; k < DST; ++k) {
      float wv = b1_k[k * E_DIM + c];
      a0 += s_lds[rg * 2 + 0][k] * wv; a1 += s_lds[rg * 2 + 1][k] * wv;
    }
    float b = b1_b[c];
    b1_lds[rg * 2 + 0][c] = a0 + b; b1_lds[rg * 2 + 1][c] = a1 + b;
  }
  __syncthreads();
  {
    int c = tid & 127, rg = tid >> 7;
    float a0 = 0.f, a1 = 0.f, a2 = 0.f, a3 = 0.f;
#pragma unroll 4
    for (int k = 0; k < HH_DIM; ++k) {
      float wv = hw1_k2[k * (2 * E_DIM) + c];
      a0 += scratch[rg * 4 + 0][k] * wv; a1 += scratch[rg * 4 + 1][k] * wv;
      a2 += scratch[rg * 4 + 2][k] * wv; a3 += scratch[rg * 4 + 3][k] * wv;
    }
    float b = hw1_b2[c];
    w1_lds[rg * 4 + 0][c] = fabsf(a0 + b); w1_lds[rg * 4 + 1][c] = fabsf(a1 + b);
    w1_lds[rg * 4 + 2][c] = fabsf(a2 + b); w1_lds[rg * 4 + 3][c] = fabsf(a3 + b);
  }
  {
    int c = tid & 63, rg = tid >> 6;
    float a0 = 0.f, a1 = 0.f;
#pragma unroll 4
    for (int k = 0; k < DST; ++k) {
      float wv = hb2_k1[k * E_DIM + c];
      a0 += s_lds[rg * 2 + 0][k] * wv; a1 += s_lds[rg * 2 + 1][k] * wv;
    }
    float b = hb2_b1[c];
    scratch2[rg * 2 + 0][c] = fmaxf(a0 + b, 0.f); scratch2[rg * 2 + 1][c] = fmaxf(a1 + b, 0.f);
  }
  __syncthreads();
  {
    int c = tid & 127, rg = tid >> 7;
    float a0 = 0.f, a1 = 0.f, a2 = 0.f, a3 = 0.f;
#pragma unroll 4
    for (int k = 0; k < DST; ++k) {
      float wv = hw2_k1[k * HH_DIM + c];
      a0 += s_lds[rg * 4 + 0][k] * wv; a1 += s_lds[rg * 4 + 1][k] * wv;
      a2 += s_lds[rg * 4 + 2][k] * wv; a3 += s_lds[rg * 4 + 3][k] * wv;
    }
    float b = hw2_b1[c];
    scratch[rg * 4 + 0][c] = fmaxf(a0 + b, 0.f); scratch[rg * 4 + 1][c] = fmaxf(a1 + b, 0.f);
    scratch[rg * 4 + 2][c] = fmaxf(a2 + b, 0.f); scratch[rg * 4 + 3][c] = fmaxf(a3 + b, 0.f);
  }
  if (tid < 64) {
    float k2v = hb2_k2[tid];
    float bias = hb2_b2[0];
#pragma unroll
    for (int r = 0; r < RPB; ++r) {
      float v = scratch2[r][tid] * k2v;
      for (int off = 32; off > 0; off >>= 1) v += __shfl_down(v, off, 64);
      if (tid == 0) b2_lds[r] = v + bias;
    }
  }
  __syncthreads();
  {
    int c = tid & 63, rg = tid >> 6;
    float a0 = 0.f, a1 = 0.f;
#pragma unroll 4
    for (int k = 0; k < HH_DIM; ++k) {
      float wv = hw2_k2[k * E_DIM + c];
      a0 += scratch[rg * 2 + 0][k] * wv; a1 += scratch[rg * 2 + 1][k] * wv;
    }
    float b = hw2_b2[c];
    w2_lds[rg * 2 + 0][c] = fabsf(a0 + b); w2_lds[rg * 2 + 1][c] = fabsf(a1 + b);
  }
  __syncthreads();
  {
    int pair = tid & 127;
    int s = pair >> 3, a = pair & 7;
    int rg = tid >> 7;
#pragma unroll
    for (int rr = 0; rr < 4; ++rr) {
      int r = rg * 4 + rr;
      float cn = cn_lds[r][s][a], qv = q_lds[r][a];
      float y = 0.f;
#pragma unroll 8
      for (int e = 0; e < E_DIM; ++e) {
        float h = fmaf(cn, w1_lds[r][e], fmaf(qv, w1_lds[r][E_DIM + e], b1_lds[r][e]));
        float act = (h > 0.f) ? h : (__expf(h) - 1.0f);
        y = fmaf(act, w2_lds[r][e], y);
      }
      red[r][pair] = fabsf(y + b2_lds[r]);
    }
  }
  __syncthreads();
  if (tid < RPB * N_AG) {
    int r = tid >> 3, a = tid & 7;
    float acc = 0.f;
#pragma unroll
    for (int ss = 0; ss < S_SAMP; ++ss) acc += red[r][ss * 8 + a];
    out[a * TB + row0 + r] = acc * (1.0f / (float)S_SAMP);
  }
}

extern "C" void kernel_launch(void* const* d_in, const int* in_sizes, int n_in,
                              void* d_out, int out_size, void* d_ws, size_t ws_size,
                              hipStream_t stream) {
  const float* q_vals = (const float*)d_in[0];
  const float* states = (const float*)d_in[1];
  const float* hw1_k1 = (const float*)d_in[2];
  const float* hw1_b1 = (const float*)d_in[3];
  const float* hw1_k2 = (const float*)d_in[4];
  const float* hw1_b2 = (const float*)d_in[5];
  const float* b1_k   = (const float*)d_in[6];
  const float* b1_b   = (const float*)d_in[7];
  const float* hw2_k1 = (const float*)d_in[8];
  const float* hw2_b1 = (const float*)d_in[9];
  const float* hw2_k2 = (const float*)d_in[10];
  const float* hw2_b2 = (const float*)d_in[11];
  const float* hb2_k1 = (const float*)d_in[12];
  const float* hb2_b1 = (const float*)d_in[13];
  const float* hb2_k2 = (const float*)d_in[14];
  const float* hb2_b2 = (const float*)d_in[15];
  float* out = (float*)d_out;

  const size_t need = ((size_t)TB * 384 + (size_t)TB * 192) * sizeof(float);
  if (ws_size >= need) {
    float* h_ws = (float*)d_ws;                 // [8192][384]
    float* w_ws = h_ws + (size_t)TB * 384;      // [8192][192]
    hyper_l1<<<dim3(TB / 64, 6), 256, 0, stream>>>(
        states, hw1_k1, hw1_b1, b1_k, b1_b, hw2_k1, hw2_b1, hb2_k1, hb2_b1, h_ws);
    hyper_l2<<<dim3(TB / 64, 3), 256, 0, stream>>>(
        h_ws, hw1_k2, hw1_b2, hw2_k2, hw2_b2, w_ws);
    alpha_main<<<dim3(TB / RPB2), 256, 0, stream>>>(
        q_vals, h_ws, w_ws, hb2_k2, hb2_b2, out);
  } else {
    alpha_fused_kernel<<<dim3(TB / RPB), 256, 0, stream>>>(
        q_vals, states, hw1_k1, hw1_b1, hw1_k2, hw1_b2, b1_k, b1_b,
        hw2_k1, hw2_b1, hw2_k2, hw2_b2, hb2_k1, hb2_b1, hb2_k2, hb2_b2, out);
  }
}

// Round 4
// 53.147 us; speedup vs baseline: 1.2404x; 1.2404x over previous
//
#include <hip/hip_runtime.h>
#include <stdint.h>

// Problem constants (from reference)
#define N_AG   8
#define S_SAMP 16
#define TB     8192      // T*B
#define DST    128       // D_STATE
#define E_DIM  64
#define HH_DIM 128

#define RPB    16        // tb-rows per block -> 512 blocks
#define W1_PAD 132       // stride % 32 == 4 -> 4 wave-rows on disjoint banks
#define E_PAD  68

__device__ __forceinline__ float4 ld4(const float* p) { return *(const float4*)p; }

// ---------------- JAX threefry2x32 (20 rounds) ----------------
__device__ __forceinline__ uint2 tf2x32(uint32_t k0, uint32_t k1,
                                        uint32_t c0, uint32_t c1) {
  uint32_t ks2 = k0 ^ k1 ^ 0x1BD11BDAu;
  uint32_t x0 = c0 + k0, x1 = c1 + k1;
#define TFR(r) { x0 += x1; x1 = (x1 << (r)) | (x1 >> (32 - (r))); x1 ^= x0; }
  TFR(13) TFR(15) TFR(26) TFR(6)
  x0 += k1;  x1 += ks2 + 1u;
  TFR(17) TFR(29) TFR(16) TFR(24)
  x0 += ks2; x1 += k0 + 2u;
  TFR(13) TFR(15) TFR(26) TFR(6)
  x0 += k0;  x1 += k1 + 3u;
  TFR(17) TFR(29) TFR(16) TFR(24)
  x0 += k1;  x1 += ks2 + 4u;
  TFR(13) TFR(15) TFR(26) TFR(6)
  x0 += ks2; x1 += k0 + 5u;
#undef TFR
  return make_uint2(x0, x1);
}

__global__ __launch_bounds__(256)
void alpha_fused2(const float* __restrict__ q_vals,   // (8, 8192)
                  const float* __restrict__ states,   // (8192, 128)
                  const float* __restrict__ hw1_k1, const float* __restrict__ hw1_b1,
                  const float* __restrict__ hw1_k2, const float* __restrict__ hw1_b2,
                  const float* __restrict__ b1_k,   const float* __restrict__ b1_b,
                  const float* __restrict__ hw2_k1, const float* __restrict__ hw2_b1,
                  const float* __restrict__ hw2_k2, const float* __restrict__ hw2_b2,
                  const float* __restrict__ hb2_k1, const float* __restrict__ hb2_b1,
                  const float* __restrict__ hb2_k2, const float* __restrict__ hb2_b2,
                  float* __restrict__ out)            // (8, 8192)
{
  __shared__ float s_lds[RPB][DST];            // states rows        8 KB
  __shared__ float scratch[RPB][HH_DIM];       // h1 then h2         8 KB
  __shared__ float scratch2[RPB][E_DIM];       // hb                 4 KB
  __shared__ float w1l[RPB][W1_PAD];           // |w1| (a|b)         8.25 KB
  __shared__ float b1l[RPB][E_PAD];            //                    4.25 KB
  __shared__ float w2l[RPB][E_PAD];            //                    4.25 KB
  __shared__ float b2l[RPB];
  __shared__ float ql[RPB][N_AG];
  __shared__ float cnred[RPB][S_SAMP][N_AG];   // cn, then |y|       8 KB

  const int tid  = threadIdx.x;
  const int row0 = blockIdx.x * RPB;
  const int r    = tid >> 4;       // row within block   (main/RNG mapping)
  const int sl   = tid & 15;       // sample

  // ---- load states (2048 floats = 512 float4) + q ----
  {
    const float4* src = reinterpret_cast<const float4*>(states + (size_t)row0 * DST);
    reinterpret_cast<float4*>(&s_lds[0][0])[tid]       = src[tid];
    reinterpret_cast<float4*>(&s_lds[0][0])[tid + 256] = src[tid + 256];
  }
  if (tid < RPB * N_AG) {
    const int rr = tid >> 3, a = tid & 7;
    ql[rr][a] = q_vals[a * TB + row0 + rr];
  }
  __syncthreads();

  // ---- RNG: one (row, sample) per thread — all 256 active ----
  {
    const uint32_t j = (uint32_t)(row0 + r) * (uint32_t)S_SAMP + (uint32_t)sl;
    uint2 kj  = tf2x32(0u, 42u, 0u, j);       // partitionable split of key(42)
    uint2 sub = tf2x32(kj.x, kj.y, 0u, 1u);   // subkey = split(key_j)[1]
    uint32_t K[N_AG];
#pragma unroll
    for (int i = 0; i < N_AG; ++i) {
      uint2 b = tf2x32(sub.x, sub.y, 0u, (uint32_t)i);
      K[i] = b.x ^ b.y;
    }
    int posa[N_AG];
#pragma unroll
    for (int i = 0; i < N_AG; ++i) {
      int rank = 0;
#pragma unroll
      for (int m = 0; m < N_AG; ++m)
        rank += (K[m] < K[i]) || (K[m] == K[i] && m < i);
      posa[rank] = i;
    }
#pragma unroll
    for (int a = 0; a < N_AG; ++a) {
      const int pa = posa[a];
      float cs = 0.f;
#pragma unroll
      for (int a2 = 0; a2 < N_AG; ++a2)
        cs += (posa[a2] < pa) ? ql[r][a2] : 0.f;
      cnred[r][sl][a] = cs / (float)max(pa, 1);
    }
  }

  // ======== GEMM phase macros: float4 k-chunks, broadcast LDS reads ========
  // 128-col phase: c = tid&127, 2 row-groups of 8 rows. 8 acc/thread.
#define PHASE128(SRC, W, BIAS, DST_ARR, DPAD, ACT)                              \
  {                                                                             \
    const int c = tid & 127, g = tid >> 7;                                      \
    float acc[8];                                                               \
    _Pragma("unroll") for (int jj = 0; jj < 8; ++jj) acc[jj] = 0.f;             \
    _Pragma("unroll 2") for (int k = 0; k < DST; k += 4) {                      \
      const float w0 = W[(k + 0) * 128 + c];                                    \
      const float w1 = W[(k + 1) * 128 + c];                                    \
      const float w2 = W[(k + 2) * 128 + c];                                    \
      const float w3 = W[(k + 3) * 128 + c];                                    \
      _Pragma("unroll") for (int jj = 0; jj < 8; ++jj) {                        \
        const float4 sv = ld4(&SRC[g * 8 + jj][k]);                             \
        acc[jj] = fmaf(sv.x, w0, acc[jj]); acc[jj] = fmaf(sv.y, w1, acc[jj]);   \
        acc[jj] = fmaf(sv.z, w2, acc[jj]); acc[jj] = fmaf(sv.w, w3, acc[jj]);   \
      }                                                                         \
    }                                                                           \
    const float bv = BIAS[c];                                                   \
    _Pragma("unroll") for (int jj = 0; jj < 8; ++jj) {                          \
      float v = acc[jj] + bv;                                                   \
      if (ACT == 1) v = fmaxf(v, 0.f);                                          \
      if (ACT == 2) v = fabsf(v);                                               \
      DST_ARR[g * 8 + jj][c] = v;                                               \
    }                                                                           \
  }
  // 64-col phase: c = tid&63, 4 row-groups of 4 rows. 4 acc/thread.
#define PHASE64(SRC, W, BIAS, DST_ARR, ACT)                                     \
  {                                                                             \
    const int c = tid & 63, g = tid >> 6;                                       \
    float acc[4];                                                               \
    _Pragma("unroll") for (int jj = 0; jj < 4; ++jj) acc[jj] = 0.f;             \
    _Pragma("unroll 2") for (int k = 0; k < DST; k += 4) {                      \
      const float w0 = W[(k + 0) * 64 + c];                                     \
      const float w1 = W[(k + 1) * 64 + c];                                     \
      const float w2 = W[(k + 2) * 64 + c];                                     \
      const float w3 = W[(k + 3) * 64 + c];                                     \
      _Pragma("unroll") for (int jj = 0; jj < 4; ++jj) {                        \
        const float4 sv = ld4(&SRC[g * 4 + jj][k]);                             \
        acc[jj] = fmaf(sv.x, w0, acc[jj]); acc[jj] = fmaf(sv.y, w1, acc[jj]);   \
        acc[jj] = fmaf(sv.z, w2, acc[jj]); acc[jj] = fmaf(sv.w, w3, acc[jj]);   \
      }                                                                         \
    }                                                                           \
    const float bv = BIAS[c];                                                   \
    _Pragma("unroll") for (int jj = 0; jj < 4; ++jj) {                          \
      float v = acc[jj] + bv;                                                   \
      if (ACT == 1) v = fmaxf(v, 0.f);                                          \
      if (ACT == 2) v = fabsf(v);                                               \
      DST_ARR[g * 4 + jj][c] = v;                                               \
    }                                                                           \
  }

  // ---- Phase 1: h1 = relu(s@hw1_k1+b) -> scratch; b1 = s@b1_k+b -> b1l ----
  PHASE128(s_lds, hw1_k1, hw1_b1, scratch, HH_DIM, 1)
  PHASE64 (s_lds, b1_k,   b1_b,   b1l,     0)
  __syncthreads();

  // ---- Phase 2: w1 = |h1@hw1_k2+b| -> w1l; hb = relu(s@hb2_k1+b) -> scratch2 ----
  PHASE128(scratch, hw1_k2, hw1_b2, w1l, W1_PAD, 2)
  PHASE64 (s_lds,   hb2_k1, hb2_b1, scratch2, 1)
  __syncthreads();

  // ---- Phase 3: h2 = relu(s@hw2_k1+b) -> scratch (overwrite h1);
  //               b2[r] = hb@hb2_k2 + b  (16-lane partial + shuffle) ----
  PHASE128(s_lds, hw2_k1, hw2_b1, scratch, HH_DIM, 1)
  {
    float v = scratch2[r][sl]      * hb2_k2[sl]
            + scratch2[r][sl + 16] * hb2_k2[sl + 16]
            + scratch2[r][sl + 32] * hb2_k2[sl + 32]
            + scratch2[r][sl + 48] * hb2_k2[sl + 48];
    v += __shfl_down(v, 8, 16); v += __shfl_down(v, 4, 16);
    v += __shfl_down(v, 2, 16); v += __shfl_down(v, 1, 16);
    if (sl == 0) b2l[r] = v + hb2_b2[0];
  }
  __syncthreads();

  // ---- Phase 4: w2 = |h2@hw2_k2+b| -> w2l ----
  PHASE64(scratch, hw2_k2, hw2_b2, w2l, 2)
  __syncthreads();

  // ---- Main: thread (r,sl) does all 8 agents; weights amortized 8x ----
  {
    float cn[N_AG], qv[N_AG], y[N_AG];
    {
      const float4 c0 = ld4(&cnred[r][sl][0]);
      const float4 c1 = ld4(&cnred[r][sl][4]);
      cn[0] = c0.x; cn[1] = c0.y; cn[2] = c0.z; cn[3] = c0.w;
      cn[4] = c1.x; cn[5] = c1.y; cn[6] = c1.z; cn[7] = c1.w;
      const float4 q0 = ld4(&ql[r][0]);
      const float4 q1 = ld4(&ql[r][4]);
      qv[0] = q0.x; qv[1] = q0.y; qv[2] = q0.z; qv[3] = q0.w;
      qv[4] = q1.x; qv[5] = q1.y; qv[6] = q1.z; qv[7] = q1.w;
    }
#pragma unroll
    for (int a = 0; a < N_AG; ++a) y[a] = 0.f;

#pragma unroll 4
    for (int e = 0; e < E_DIM; e += 4) {
      const float4 wa  = ld4(&w1l[r][e]);
      const float4 wb  = ld4(&w1l[r][64 + e]);
      const float4 bb  = ld4(&b1l[r][e]);
      const float4 w2v = ld4(&w2l[r][e]);
#pragma unroll
      for (int a = 0; a < N_AG; ++a) {
        float h;
        h = fmaf(cn[a], wa.x, fmaf(qv[a], wb.x, bb.x));
        y[a] = fmaf((h > 0.f) ? h : (__expf(h) - 1.f), w2v.x, y[a]);
        h = fmaf(cn[a], wa.y, fmaf(qv[a], wb.y, bb.y));
        y[a] = fmaf((h > 0.f) ? h : (__expf(h) - 1.f), w2v.y, y[a]);
        h = fmaf(cn[a], wa.z, fmaf(qv[a], wb.z, bb.z));
        y[a] = fmaf((h > 0.f) ? h : (__expf(h) - 1.f), w2v.z, y[a]);
        h = fmaf(cn[a], wa.w, fmaf(qv[a], wb.w, bb.w));
        y[a] = fmaf((h > 0.f) ? h : (__expf(h) - 1.f), w2v.w, y[a]);
      }
    }
    const float b2v = b2l[r];
    // overwrite own cn slots with |y| (no cross-thread hazard: same slots)
    *(float4*)&cnred[r][sl][0] =
        make_float4(fabsf(y[0] + b2v), fabsf(y[1] + b2v), fabsf(y[2] + b2v), fabsf(y[3] + b2v));
    *(float4*)&cnred[r][sl][4] =
        make_float4(fabsf(y[4] + b2v), fabsf(y[5] + b2v), fabsf(y[6] + b2v), fabsf(y[7] + b2v));
  }
  __syncthreads();

  // ---- Reduce over samples; a = tid>>4 so 16 consecutive rows coalesce ----
  if (tid < RPB * N_AG) {
    const int a = tid >> 4, rr = tid & 15;
    float acc = 0.f;
#pragma unroll
    for (int ss = 0; ss < S_SAMP; ++ss) acc += cnred[rr][ss][a];
    out[a * TB + row0 + rr] = acc * (1.0f / (float)S_SAMP);
  }
#undef PHASE128
#undef PHASE64
}

extern "C" void kernel_launch(void* const* d_in, const int* in_sizes, int n_in,
                              void* d_out, int out_size, void* d_ws, size_t ws_size,
                              hipStream_t stream) {
  const float* q_vals = (const float*)d_in[0];
  const float* states = (const float*)d_in[1];
  const float* hw1_k1 = (const float*)d_in[2];
  const float* hw1_b1 = (const float*)d_in[3];
  const float* hw1_k2 = (const float*)d_in[4];
  const float* hw1_b2 = (const float*)d_in[5];
  const float* b1_k   = (const float*)d_in[6];
  const float* b1_b   = (const float*)d_in[7];
  const float* hw2_k1 = (const float*)d_in[8];
  const float* hw2_b1 = (const float*)d_in[9];
  const float* hw2_k2 = (const float*)d_in[10];
  const float* hw2_b2 = (const float*)d_in[11];
  const float* hb2_k1 = (const float*)d_in[12];
  const float* hb2_b1 = (const float*)d_in[13];
  const float* hb2_k2 = (const float*)d_in[14];
  const float* hb2_b2 = (const float*)d_in[15];
  float* out = (float*)d_out;

  alpha_fused2<<<dim3(TB / RPB), 256, 0, stream>>>(
      q_vals, states, hw1_k1, hw1_b1, hw1_k2, hw1_b2, b1_k, b1_b,
      hw2_k1, hw2_b1, hw2_k2, hw2_b2, hb2_k1, hb2_b1, hb2_k2, hb2_b2, out);
}